// Round 3
// baseline (125.243 us; speedup 1.0000x reference)
//
#include <hip/hip_runtime.h>

// AnnularDilatedKNN: B=4, N=4096, C=64, SAMPLE=16, DILATED_RATE=2, r^2=256.
// Round 6: sorted-order query + prefetched chunk loop + 1-barrier blocks.
//  - K1 preprocess (4 blocks, 1/batch): LDS histogram -> scan -> scatter,
//    hist index padded (c + c/32) so the serial 32-cell scan is bank-conflict
//    free. P[j]=(x,y,z,sq) in ORIGINAL order; SP[s]=(x,y,z,bitcast orig idx)
//    in CELL-SORTED order; CS = cell starts.
//  - K2 query_gather: block handles 4 consecutive SORTED points (spatially
//    adjacent -> near-equal work per wave + L1 reuse of candidates/cellStart).
//    Per-wave 3x3x3 query, 9 segments flattened via constant-indexed select
//    chain, chunk loop DOUBLE-BUFFERED (prefetch next float4; prefetch index
//    clamped to T-1 -- duplicate tests harmless: hits are an idempotent
//    bitmask OR and first-hit/ranks are derived from the mask). Each wave
//    zeros/reads only its own mask -> single __syncthreads before gather.
//  - Hit test bit-identical to reference: sq=(x*x+y*y)+z*z,
//    dot=(xi*xj+yi*yj)+zi*zj, d2=(sqi+sqj)-2*dot, contract off.
//  - Gather: output column = orig_idx*16+k (64-B runs per point, coalesced).

#define BB 4
#define NN 4096
#define KK 16
#define PLANE (NN * KK)   // 65536
#define NC 20
#define NCELLS (NC * NC * NC)   // 8000
#define HP(c) ((c) + ((c) >> 5))   // padded hist index: bank = (t + i) % 32

__device__ __forceinline__ int cell1d(float v)
{
    int c = (int)floorf((v + 160.0f) * 0.0625f);
    c = c < 0 ? 0 : c;
    return c > (NC - 1) ? (NC - 1) : c;
}

// ---------- K1: per-batch histogram -> scan -> scatter (1 block per batch) ----------
__global__ __launch_bounds__(256)
void preprocess(const float* __restrict__ xyz, float4* __restrict__ P,
                float4* __restrict__ SP, int* __restrict__ CS)
{
#pragma clang fp contract(off)
    __shared__ int hist[HP(NCELLS - 1) + 1 + 8];   // ~33 KB, padded
    __shared__ int wsum[4];

    const int b = blockIdx.x;
    const int t = threadIdx.x;
    const int lane = t & 63, wave = t >> 6;
    const float* xb = xyz + b * NN * 3;

    for (int c = t; c < NCELLS; c += 256) hist[HP(c)] = 0;
    __syncthreads();

    // pass 1: build P + LDS histogram
    for (int i = t; i < NN; i += 256) {
        const float x = xb[3 * i], y = xb[3 * i + 1], z = xb[3 * i + 2];
        const float sq = (x * x + y * y) + z * z;
        P[(b << 12) + i] = make_float4(x, y, z, sq);
        const int c = (cell1d(z) * NC + cell1d(y)) * NC + cell1d(x);
        atomicAdd(&hist[HP(c)], 1);
    }
    __syncthreads();

    // in-block exclusive scan; hist becomes the scatter cursor
    const int c0 = t * 32;
    const int c1 = (c0 + 32 < NCELLS) ? c0 + 32 : NCELLS;
    int s = 0;
    for (int c = c0; c < c1; ++c) s += hist[HP(c)];
    int x = s;
#pragma unroll
    for (int off = 1; off < 64; off <<= 1) {
        const int u = __shfl_up(x, off, 64);
        if (lane >= off) x += u;
    }
    if (lane == 63) wsum[wave] = x;
    __syncthreads();
    int wb = 0;
    for (int w = 0; w < wave; ++w) wb += wsum[w];
    int acc = wb + x - s;

    int* cs = CS + b * (NCELLS + 1);
    for (int c = c0; c < c1; ++c) {
        const int v = hist[HP(c)];
        cs[c]      = acc;
        hist[HP(c)] = acc;
        acc += v;
    }
    if (t == 0) cs[NCELLS] = NN;
    __syncthreads();

    // pass 2: scatter into cell-sorted order; SP.w carries original index
    for (int i = t; i < NN; i += 256) {
        const float x = xb[3 * i], y = xb[3 * i + 1], z = xb[3 * i + 2];
        const int c = (cell1d(z) * NC + cell1d(y)) * NC + cell1d(x);
        const int slot = atomicAdd(&hist[HP(c)], 1);
        SP[(b << 12) + slot] = make_float4(x, y, z, __int_as_float(i));
    }
}

// ---------- K2: fused grid ball query + gather, sorted point order ----------
// grid: 4096 blocks x 256 threads; block handles 4 consecutive SORTED points,
// wave w queries sorted point q0+w.
__global__ __launch_bounds__(256, 4)
void query_gather(const float4* __restrict__ P, const float4* __restrict__ SP,
                  const int* __restrict__ CS, const float* __restrict__ feat,
                  float* __restrict__ out)
{
#pragma clang fp contract(off)
    __shared__ unsigned int mask[4][128];   // 4096-bit hit mask per point
    __shared__ int sids[4 * KK];
    __shared__ int jof[4];                  // original index of each point

    const int beta = blockIdx.x;
    const int b    = beta >> 10;
    const int q0   = (beta & 1023) * 4;     // first sorted point of block
    const int t    = threadIdx.x;
    const int lane = t & 63;
    const int wave = t >> 6;

    const float4* Pb  = P  + (b << 12);
    const float4* Sb  = SP + (b << 12);
    const int*    csb = CS + b * (NCELLS + 1);

    const float4 pr  = Sb[q0 + wave];               // own point (sorted)
    const float  sqi = (pr.x * pr.x + pr.y * pr.y) + pr.z * pr.z;
    if (lane == 0) jof[wave] = __float_as_int(pr.w);

    // zero own mask (own-wave use only -> no barrier needed)
    unsigned int* m = mask[wave];
    m[2 * lane]     = 0u;
    m[2 * lane + 1] = 0u;

    // ---- query: 3x3x3 cells, flattened + prefetched candidate loop ----
    {
        const int cx = cell1d(pr.x), cy = cell1d(pr.y), cz = cell1d(pr.z);
        const int xlo = cx > 0 ? cx - 1 : 0;
        const int xhi = cx < NC - 1 ? cx + 1 : NC - 1;

        int ss[9], se[9];
#pragma unroll
        for (int dz = 0; dz < 3; ++dz)
#pragma unroll
            for (int dy = 0; dy < 3; ++dy) {
                int zz = cz + dz - 1; zz = zz < 0 ? 0 : (zz > NC - 1 ? NC - 1 : zz);
                int yy = cy + dy - 1; yy = yy < 0 ? 0 : (yy > NC - 1 ? NC - 1 : yy);
                const int cb = (zz * NC + yy) * NC;
                ss[dz * 3 + dy] = csb[cb + xlo];
                se[dz * 3 + dy] = csb[cb + xhi + 1];   // x-run contiguous
            }

        int off[10], base[9];
        off[0] = 0;
#pragma unroll
        for (int i = 0; i < 9; ++i) {
            off[i + 1] = off[i] + (se[i] - ss[i]);
            base[i]    = ss[i] - off[i];
        }
        const int T = off[9];                // >= 1 (own cell contains self)

        auto sbaddr = [&](int u) {
            int bs = base[0];
#pragma unroll
            for (int i = 1; i < 9; ++i) bs = (u >= off[i]) ? base[i] : bs;
            return u + bs;
        };

        const int nch = (T + 63) >> 6;
        float4 a = Sb[sbaddr(lane < T ? lane : T - 1)];
        for (int c = 0; c < nch; ++c) {
            float4 nx;
            if (c + 1 < nch) {
                const int un0 = lane + ((c + 1) << 6);
                nx = Sb[sbaddr(un0 < T ? un0 : T - 1)];
            }
            const float sqj = (a.x * a.x + a.y * a.y) + a.z * a.z;
            const float dot = (pr.x * a.x + pr.y * a.y) + pr.z * a.z;
            const float d2  = (sqi + sqj) - 2.0f * dot;
            if (d2 < 256.0f) {                       // duplicates harmless (OR)
                const int j = __float_as_int(a.w);
                atomicOr(&m[j >> 5], 1u << (j & 31));
            }
            a = nx;
        }
    }

    // ---- rank extraction: lane l owns indices [64l, 64l+64) (own mask) ----
    {
        const unsigned int lo  = m[2 * lane];
        const unsigned int hiw = m[2 * lane + 1];
        const unsigned long long w = ((unsigned long long)hiw << 32) | lo;
        const int c = __popcll(w);
        int x = c;                                  // inclusive scan of counts
#pragma unroll
        for (int off = 1; off < 64; off <<= 1) {
            const int u = __shfl_up(x, off, 64);
            if (lane >= off) x += u;
        }
        const int cnt  = __shfl(x, 63, 64);         // total hits
        const int base = x - c;                     // hits before this lane

        int fj = 0x7fffffff;                        // global first hit
        if (w) fj = (lane << 6) + __builtin_ctzll(w);
        for (int off = 32; off; off >>= 1) {
            const int o = __shfl_xor(fj, off, 64);
            fj = fj < o ? fj : o;
        }

        int* row = sids + wave * KK;
        if (w && base <= 30 && base + c > 16) {     // lane covers ranks 16..30?
            unsigned long long ww = w;
            int r = base;
            while (ww) {
                if (r > 30) break;
                if (r >= 16) row[r - 15] = (lane << 6) + __builtin_ctzll(ww);
                ww &= ww - 1;
                ++r;
            }
        }
        const int hi = (cnt < 31 ? cnt : 31) - 16;
        if (lane < KK && (lane == 0 || lane > hi)) row[lane] = fj;
    }
    __syncthreads();

    // ---- gather: thread t -> (point rowi>>4, k rowi&15), channel quarter t>>6 ----
    const int rowi = t & 63;
    const int part = t >> 6;
    const int id   = sids[rowi];
    const int ob   = jof[rowi >> 4] * KK + (rowi & 15);

    if (part == 0) {                                // dilated_xyz [B,3,N,K]
        const float4 p = Pb[id];
        float* o0 = out + (size_t)b * 3 * PLANE + ob;
        o0[0]         = p.x;
        o0[PLANE]     = p.y;
        o0[2 * PLANE] = p.z;
    }

    // dilated_feature [B,64,N,K], channels [16*part, 16*part+16)
    const float4* frow = reinterpret_cast<const float4*>(feat + ((size_t)(b << 12) + id) * 64) + part * 4;
    float* o1 = out + (size_t)BB * 3 * PLANE + (size_t)b * 64 * PLANE
                    + (size_t)(part * 16) * PLANE + ob;
#pragma unroll
    for (int q = 0; q < 4; ++q) {
        const float4 v = frow[q];
        float* oc = o1 + (size_t)(4 * q) * PLANE;
        oc[0]         = v.x;
        oc[PLANE]     = v.y;
        oc[2 * PLANE] = v.z;
        oc[3 * PLANE] = v.w;
    }
}

extern "C" void kernel_launch(void* const* d_in, const int* in_sizes, int n_in,
                              void* d_out, int out_size, void* d_ws, size_t ws_size,
                              hipStream_t stream) {
    const float* xyz  = (const float*)d_in[0];
    const float* feat = (const float*)d_in[1];
    float* out = (float*)d_out;

    char* ws = (char*)d_ws;
    float4* P  = (float4*)(ws);                // 16384*16 = 262144
    float4* SP = (float4*)(ws + 262144);       // 262144
    int*    CS = (int*)   (ws + 524288);       // 4*8001*4 = 128016 (total ~652 KB)

    preprocess  <<<BB,          256, 0, stream>>>(xyz, P, SP, CS);
    query_gather<<<BB * NN / 4, 256, 0, stream>>>(P, SP, CS, feat, out);
}

// Round 6
// 114.113 us; speedup vs baseline: 1.0975x; 1.0975x over previous
//
#include <hip/hip_runtime.h>

// AnnularDilatedKNN: B=4, N=4096, C=64, SAMPLE=16, DILATED_RATE=2, r^2=256.
// Round 9: 2D-grid query -> 3 contiguous runs, zero per-thread arrays.
//  Crash post-mortem (r7,r8): both aborts share only the lane-per-run/shfl
//  query; removed entirely. This round = round-5 kernel (PASSED, 115.4us)
//  with the query phase replaced by the simplest possible structure:
//  - Grid is 2D (x,y only), cell 16x16, 20x20=400 cells over [-160,160)
//    (clamped; clamping/duplicates only add candidates, distance test
//    filters; hit recording is an idempotent bitmask OR).
//  - Neighborhood = 3 y-rows x contiguous x-run: bounds are 6 register
//    scalars, loops fully guarded (no speculative loads, no shfl bounds,
//    no per-thread arrays -> nothing for the compiler to demote; fixes the
//    r6 spill pathology: VGPR=24/LDS=11776 -> 72% stall).
//  - Hit test bit-identical to reference: sq=(x*x+y*y)+z*z,
//    dot=(xi*xj+yi*yj)+zi*zj, d2=(sqi+sqj)-2*dot, contract off.
//  - Rank recovery (4096-bit LDS mask + popcount scan) and gather phase
//    verbatim from the passed round-5 kernel; original point order.

#define BB 4
#define NN 4096
#define KK 16
#define PLANE (NN * KK)   // 65536
#define NC 20
#define NCELL2 (NC * NC)  // 400

__device__ __forceinline__ int cell1d(float v)
{
    int c = (int)floorf((v + 160.0f) * 0.0625f);
    c = c < 0 ? 0 : c;
    return c > (NC - 1) ? (NC - 1) : c;
}

// ---------- K1: per-batch 2D histogram -> scan -> scatter (1 block/batch) ----------
__global__ __launch_bounds__(256)
void preprocess(const float* __restrict__ xyz, float4* __restrict__ P,
                float4* __restrict__ SP, int* __restrict__ CS)
{
#pragma clang fp contract(off)
    __shared__ int hist[NCELL2];
    __shared__ int wsum[4];

    const int b = blockIdx.x;
    const int t = threadIdx.x;
    const int lane = t & 63, wave = t >> 6;
    const float* xb = xyz + b * NN * 3;

    if (t < NCELL2) hist[t] = 0;
    if (t + 256 < NCELL2) hist[t + 256] = 0;
    __syncthreads();

    // pass 1: build P + LDS histogram (2D cell from x,y)
    for (int i = t; i < NN; i += 256) {
        const float x = xb[3 * i], y = xb[3 * i + 1], z = xb[3 * i + 2];
        const float sq = (x * x + y * y) + z * z;
        P[(b << 12) + i] = make_float4(x, y, z, sq);
        const int c = cell1d(y) * NC + cell1d(x);
        atomicAdd(&hist[c], 1);
    }
    __syncthreads();

    // in-block exclusive scan over 400 cells; hist becomes scatter cursor
    const int c0 = t * 2;
    const int c1 = (c0 + 2 < NCELL2) ? c0 + 2 : NCELL2;
    int s = 0;
    for (int c = c0; c < c1; ++c) s += hist[c];
    int x = s;
#pragma unroll
    for (int off = 1; off < 64; off <<= 1) {
        const int u = __shfl_up(x, off, 64);
        if (lane >= off) x += u;
    }
    if (lane == 63) wsum[wave] = x;
    __syncthreads();
    int wb = 0;
    for (int w = 0; w < wave; ++w) wb += wsum[w];
    int acc = wb + x - s;

    int* cs = CS + b * (NCELL2 + 1);
    for (int c = c0; c < c1; ++c) {
        const int v = hist[c];
        cs[c]   = acc;
        hist[c] = acc;
        acc += v;
    }
    if (t == 0) cs[NCELL2] = NN;
    __syncthreads();

    // pass 2: scatter into cell-sorted order; SP.w carries original index
    for (int i = t; i < NN; i += 256) {
        const float x = xb[3 * i], y = xb[3 * i + 1], z = xb[3 * i + 2];
        const int c = cell1d(y) * NC + cell1d(x);
        const int slot = atomicAdd(&hist[c], 1);
        SP[(b << 12) + slot] = make_float4(x, y, z, __int_as_float(i));
    }
}

// ---------- K2: fused grid ball query + gather ----------
// grid: 4096 blocks x 256 threads; block handles 4 consecutive points
// (ORIGINAL order), wave w queries point p0+w via 3 contiguous runs.
__global__ __launch_bounds__(256, 4)
void query_gather(const float4* __restrict__ P, const float4* __restrict__ SP,
                  const int* __restrict__ CS, const float* __restrict__ feat,
                  float* __restrict__ out)
{
#pragma clang fp contract(off)
    __shared__ unsigned int mask[4][128];   // 4096-bit hit mask per point
    __shared__ int sids[4 * KK];

    const int beta = blockIdx.x;
    const int b    = beta >> 10;
    const int p0   = (beta & 1023) * 4;
    const int t    = threadIdx.x;
    const int lane = t & 63;
    const int wave = t >> 6;

    const float4* Pb  = P  + (b << 12);
    const float4* Sb  = SP + (b << 12);
    const int*    csb = CS + b * (NCELL2 + 1);

    const float4 pi  = Pb[p0 + wave];               // own point (original order)
    const float  sqi = pi.w;

    // zero own mask (own-wave use only -> no barrier needed before query)
    unsigned int* m = mask[wave];
    m[2 * lane]     = 0u;
    m[2 * lane + 1] = 0u;

    // ---- query: 3 y-rows, each a contiguous x-run; all bounds in registers ----
    {
        const int cx = cell1d(pi.x), cy = cell1d(pi.y);
        const int xlo = cx > 0 ? cx - 1 : 0;
        const int xhi = cx < NC - 1 ? cx + 1 : NC - 1;
#pragma unroll
        for (int rr = 0; rr < 3; ++rr) {
            int yy = cy + rr - 1;
            yy = yy < 0 ? 0 : (yy > NC - 1 ? NC - 1 : yy);   // dup rows harmless (OR)
            const int cb = yy * NC;
            const int s  = csb[cb + xlo];
            const int e  = csb[cb + xhi + 1];                 // x-run contiguous
            for (int v = s + lane; v < e; v += 64) {          // guarded loads only
                const float4 a = Sb[v];
                const float sqj = (a.x * a.x + a.y * a.y) + a.z * a.z;
                const float dot = (pi.x * a.x + pi.y * a.y) + pi.z * a.z;
                const float d2  = (sqi + sqj) - 2.0f * dot;
                if (d2 < 256.0f) {
                    const int j = __float_as_int(a.w);
                    atomicOr(&m[j >> 5], 1u << (j & 31));
                }
            }
        }
    }

    // ---- rank extraction: lane l owns indices [64l, 64l+64) (own mask) ----
    {
        const unsigned int lo  = m[2 * lane];
        const unsigned int hiw = m[2 * lane + 1];
        const unsigned long long w = ((unsigned long long)hiw << 32) | lo;
        const int c = __popcll(w);
        int x = c;                                  // inclusive scan of counts
#pragma unroll
        for (int off = 1; off < 64; off <<= 1) {
            const int u = __shfl_up(x, off, 64);
            if (lane >= off) x += u;
        }
        const int cnt  = __shfl(x, 63, 64);         // total hits
        const int base = x - c;                     // hits before this lane

        int fj = 0x7fffffff;                        // global first hit
        if (w) fj = (lane << 6) + __builtin_ctzll(w);
        for (int off = 32; off; off >>= 1) {
            const int o = __shfl_xor(fj, off, 64);
            fj = fj < o ? fj : o;
        }

        int* row = sids + wave * KK;
        if (w && base <= 30 && base + c > 16) {     // lane covers ranks 16..30?
            unsigned long long ww = w;
            int r = base;
            while (ww) {
                if (r > 30) break;
                if (r >= 16) row[r - 15] = (lane << 6) + __builtin_ctzll(ww);
                ww &= ww - 1;
                ++r;
            }
        }
        const int hi = (cnt < 31 ? cnt : 31) - 16;
        if (lane < KK && (lane == 0 || lane > hi)) row[lane] = fj;
    }
    __syncthreads();

    // ---- gather: thread t -> output row (t&63), channel quarter (t>>6) ----
    const int rowi = t & 63;
    const int part = t >> 6;
    const int id   = sids[rowi];
    const int ob   = (beta & 1023) * 64 + rowi;

    if (part == 0) {                                // dilated_xyz [B,3,N,K]
        const float4 p = Pb[id];
        float* o0 = out + (size_t)b * 3 * PLANE + ob;
        o0[0]         = p.x;
        o0[PLANE]     = p.y;
        o0[2 * PLANE] = p.z;
    }

    // dilated_feature [B,64,N,K], channels [16*part, 16*part+16)
    const float4* frow = reinterpret_cast<const float4*>(feat + ((size_t)(b << 12) + id) * 64) + part * 4;
    float* o1 = out + (size_t)BB * 3 * PLANE + (size_t)b * 64 * PLANE
                    + (size_t)(part * 16) * PLANE + ob;
#pragma unroll
    for (int q = 0; q < 4; ++q) {
        const float4 v = frow[q];
        float* oc = o1 + (size_t)(4 * q) * PLANE;
        oc[0]         = v.x;
        oc[PLANE]     = v.y;
        oc[2 * PLANE] = v.z;
        oc[3 * PLANE] = v.w;
    }
}

extern "C" void kernel_launch(void* const* d_in, const int* in_sizes, int n_in,
                              void* d_out, int out_size, void* d_ws, size_t ws_size,
                              hipStream_t stream) {
    const float* xyz  = (const float*)d_in[0];
    const float* feat = (const float*)d_in[1];
    float* out = (float*)d_out;

    char* ws = (char*)d_ws;
    float4* P  = (float4*)(ws);                // 16384*16 = 262144
    float4* SP = (float4*)(ws + 262144);       // 262144
    int*    CS = (int*)   (ws + 524288);       // 4*401*4 = 6416 (total ~531 KB)

    preprocess  <<<BB,          256, 0, stream>>>(xyz, P, SP, CS);
    query_gather<<<BB * NN / 4, 256, 0, stream>>>(P, SP, CS, feat, out);
}

// Round 7
// 107.064 us; speedup vs baseline: 1.1698x; 1.0658x over previous
//
#include <hip/hip_runtime.h>

// AnnularDilatedKNN: B=4, N=4096, C=64, SAMPLE=16, DILATED_RATE=2, r^2=256.
// Round 10: remove P array + single-pass 1024-thread preprocess.
//  Round-6 (PASSED 114.1us) budget: 46us fill (harness poison, fixed) +
//  ~15us gaps + ~53us K1+K2. K1 ran on 4 CUs reading xyz twice + writing
//  P & SP => ~20us BW/latency-bound. Fixes:
//  - No P workspace: K2 loads its own 4 points from xyz (wave-uniform scalar
//    loads; sq recomputed with the bit-identical formula) and gathers xyz
//    output channels from xyz[3*id] (L2-hot). K1 writes only SP + CS.
//  - K1: 1024 threads/block, 4 points/thread via 3 coalesced float4 loads,
//    coords kept in registers (static indexing only), LDS 400-cell histogram,
//    wave-0 scan (7 cells/lane, fully unrolled), scatter from registers.
//    xyz read ONCE; 16 waves/block.
//  - K2 query/rank/gather logic verbatim from round-6 (2D grid 20x20 cell 16,
//    3 contiguous y-runs, guarded loads only, 4096-bit mask + popcount ranks).
//  - Hit test bit-identical to reference: sq=(x*x+y*y)+z*z,
//    dot=(xi*xj+yi*yj)+zi*zj, d2=(sqi+sqj)-2*dot, contract off.

#define BB 4
#define NN 4096
#define KK 16
#define PLANE (NN * KK)   // 65536
#define NC 20
#define NCELL2 (NC * NC)  // 400

__device__ __forceinline__ int cell1d(float v)
{
    int c = (int)floorf((v + 160.0f) * 0.0625f);
    c = c < 0 ? 0 : c;
    return c > (NC - 1) ? (NC - 1) : c;
}

// ---------- K1: per-batch 2D histogram -> scan -> scatter (1 block/batch) ----------
// 1024 threads; thread t owns points 4t..4t+3 of its batch.
__global__ __launch_bounds__(1024)
void preprocess(const float* __restrict__ xyz, float4* __restrict__ SP,
                int* __restrict__ CS)
{
#pragma clang fp contract(off)
    __shared__ int hist[NCELL2];

    const int b = blockIdx.x;
    const int t = threadIdx.x;
    const float4* xb4 = (const float4*)(xyz + (size_t)b * NN * 3);

    if (t < NCELL2) hist[t] = 0;
    __syncthreads();

    // load 4 consecutive points (3 coalesced float4), keep in registers
    const float4 v0 = xb4[3 * t];
    const float4 v1 = xb4[3 * t + 1];
    const float4 v2 = xb4[3 * t + 2];
    const float px0 = v0.x, py0 = v0.y, pz0 = v0.z;
    const float px1 = v0.w, py1 = v1.x, pz1 = v1.y;
    const float px2 = v1.z, py2 = v1.w, pz2 = v2.x;
    const float px3 = v2.y, py3 = v2.z, pz3 = v2.w;
    const int c0 = cell1d(py0) * NC + cell1d(px0);
    const int c1 = cell1d(py1) * NC + cell1d(px1);
    const int c2 = cell1d(py2) * NC + cell1d(px2);
    const int c3 = cell1d(py3) * NC + cell1d(px3);
    atomicAdd(&hist[c0], 1);
    atomicAdd(&hist[c1], 1);
    atomicAdd(&hist[c2], 1);
    atomicAdd(&hist[c3], 1);
    __syncthreads();

    // wave 0 scans the 400 cells (7 cells per lane, statically indexed)
    if (t < 64) {
        const int base = t * 7;
        int loc0 = 0, loc1 = 0, loc2 = 0, loc3 = 0, loc4 = 0, loc5 = 0, loc6 = 0;
        if (base + 0 < NCELL2) loc0 = hist[base + 0];
        if (base + 1 < NCELL2) loc1 = hist[base + 1];
        if (base + 2 < NCELL2) loc2 = hist[base + 2];
        if (base + 3 < NCELL2) loc3 = hist[base + 3];
        if (base + 4 < NCELL2) loc4 = hist[base + 4];
        if (base + 5 < NCELL2) loc5 = hist[base + 5];
        if (base + 6 < NCELL2) loc6 = hist[base + 6];
        const int s = loc0 + loc1 + loc2 + loc3 + loc4 + loc5 + loc6;
        int x = s;
#pragma unroll
        for (int off = 1; off < 64; off <<= 1) {
            const int u = __shfl_up(x, off, 64);
            if (t >= off) x += u;
        }
        int acc = x - s;                       // exclusive prefix
        int* cs = CS + b * (NCELL2 + 1);
        if (base + 0 < NCELL2) { cs[base + 0] = acc; hist[base + 0] = acc; acc += loc0; }
        if (base + 1 < NCELL2) { cs[base + 1] = acc; hist[base + 1] = acc; acc += loc1; }
        if (base + 2 < NCELL2) { cs[base + 2] = acc; hist[base + 2] = acc; acc += loc2; }
        if (base + 3 < NCELL2) { cs[base + 3] = acc; hist[base + 3] = acc; acc += loc3; }
        if (base + 4 < NCELL2) { cs[base + 4] = acc; hist[base + 4] = acc; acc += loc4; }
        if (base + 5 < NCELL2) { cs[base + 5] = acc; hist[base + 5] = acc; acc += loc5; }
        if (base + 6 < NCELL2) { cs[base + 6] = acc; hist[base + 6] = acc; acc += loc6; }
        if (t == 0) cs[NCELL2] = NN;
    }
    __syncthreads();

    // scatter from registers; SP.w carries original index
    {
        int slot;
        slot = atomicAdd(&hist[c0], 1);
        SP[(b << 12) + slot] = make_float4(px0, py0, pz0, __int_as_float(4 * t + 0));
        slot = atomicAdd(&hist[c1], 1);
        SP[(b << 12) + slot] = make_float4(px1, py1, pz1, __int_as_float(4 * t + 1));
        slot = atomicAdd(&hist[c2], 1);
        SP[(b << 12) + slot] = make_float4(px2, py2, pz2, __int_as_float(4 * t + 2));
        slot = atomicAdd(&hist[c3], 1);
        SP[(b << 12) + slot] = make_float4(px3, py3, pz3, __int_as_float(4 * t + 3));
    }
}

// ---------- K2: fused grid ball query + gather ----------
// grid: 4096 blocks x 256 threads; block handles 4 consecutive points
// (ORIGINAL order), wave w queries point p0+w via 3 contiguous runs.
__global__ __launch_bounds__(256, 4)
void query_gather(const float* __restrict__ xyz, const float4* __restrict__ SP,
                  const int* __restrict__ CS, const float* __restrict__ feat,
                  float* __restrict__ out)
{
#pragma clang fp contract(off)
    __shared__ unsigned int mask[4][128];   // 4096-bit hit mask per point
    __shared__ int sids[4 * KK];

    const int beta = blockIdx.x;
    const int b    = beta >> 10;
    const int p0   = (beta & 1023) * 4;
    const int t    = threadIdx.x;
    const int lane = t & 63;
    const int wave = t >> 6;

    const float* xb   = xyz + (size_t)b * NN * 3;
    const float4* Sb  = SP + (b << 12);
    const int*    csb = CS + b * (NCELL2 + 1);

    // own point (original order): wave-uniform scalar loads, sq bit-identical
    const int   ip  = p0 + wave;
    const float pix = xb[3 * ip];
    const float piy = xb[3 * ip + 1];
    const float piz = xb[3 * ip + 2];
    const float sqi = (pix * pix + piy * piy) + piz * piz;

    // zero own mask (own-wave use only -> no barrier needed before query)
    unsigned int* m = mask[wave];
    m[2 * lane]     = 0u;
    m[2 * lane + 1] = 0u;

    // ---- query: 3 y-rows, each a contiguous x-run; all bounds in registers ----
    {
        const int cx = cell1d(pix), cy = cell1d(piy);
        const int xlo = cx > 0 ? cx - 1 : 0;
        const int xhi = cx < NC - 1 ? cx + 1 : NC - 1;
#pragma unroll
        for (int rr = 0; rr < 3; ++rr) {
            int yy = cy + rr - 1;
            yy = yy < 0 ? 0 : (yy > NC - 1 ? NC - 1 : yy);   // dup rows harmless (OR)
            const int cb = yy * NC;
            const int s  = csb[cb + xlo];
            const int e  = csb[cb + xhi + 1];                 // x-run contiguous
            for (int v = s + lane; v < e; v += 64) {          // guarded loads only
                const float4 a = Sb[v];
                const float sqj = (a.x * a.x + a.y * a.y) + a.z * a.z;
                const float dot = (pix * a.x + piy * a.y) + piz * a.z;
                const float d2  = (sqi + sqj) - 2.0f * dot;
                if (d2 < 256.0f) {
                    const int j = __float_as_int(a.w);
                    atomicOr(&m[j >> 5], 1u << (j & 31));
                }
            }
        }
    }

    // ---- rank extraction: lane l owns indices [64l, 64l+64) (own mask) ----
    {
        const unsigned int lo  = m[2 * lane];
        const unsigned int hiw = m[2 * lane + 1];
        const unsigned long long w = ((unsigned long long)hiw << 32) | lo;
        const int c = __popcll(w);
        int x = c;                                  // inclusive scan of counts
#pragma unroll
        for (int off = 1; off < 64; off <<= 1) {
            const int u = __shfl_up(x, off, 64);
            if (lane >= off) x += u;
        }
        const int cnt  = __shfl(x, 63, 64);         // total hits
        const int base = x - c;                     // hits before this lane

        int fj = 0x7fffffff;                        // global first hit
        if (w) fj = (lane << 6) + __builtin_ctzll(w);
        for (int off = 32; off; off >>= 1) {
            const int o = __shfl_xor(fj, off, 64);
            fj = fj < o ? fj : o;
        }

        int* row = sids + wave * KK;
        if (w && base <= 30 && base + c > 16) {     // lane covers ranks 16..30?
            unsigned long long ww = w;
            int r = base;
            while (ww) {
                if (r > 30) break;
                if (r >= 16) row[r - 15] = (lane << 6) + __builtin_ctzll(ww);
                ww &= ww - 1;
                ++r;
            }
        }
        const int hi = (cnt < 31 ? cnt : 31) - 16;
        if (lane < KK && (lane == 0 || lane > hi)) row[lane] = fj;
    }
    __syncthreads();

    // ---- gather: thread t -> output row (t&63), channel quarter (t>>6) ----
    const int rowi = t & 63;
    const int part = t >> 6;
    const int id   = sids[rowi];
    const int ob   = (beta & 1023) * 64 + rowi;

    if (part == 0) {                                // dilated_xyz [B,3,N,K]
        float* o0 = out + (size_t)b * 3 * PLANE + ob;
        o0[0]         = xb[3 * id];
        o0[PLANE]     = xb[3 * id + 1];
        o0[2 * PLANE] = xb[3 * id + 2];
    }

    // dilated_feature [B,64,N,K], channels [16*part, 16*part+16)
    const float4* frow = reinterpret_cast<const float4*>(feat + ((size_t)(b << 12) + id) * 64) + part * 4;
    float* o1 = out + (size_t)BB * 3 * PLANE + (size_t)b * 64 * PLANE
                    + (size_t)(part * 16) * PLANE + ob;
#pragma unroll
    for (int q = 0; q < 4; ++q) {
        const float4 v = frow[q];
        float* oc = o1 + (size_t)(4 * q) * PLANE;
        oc[0]         = v.x;
        oc[PLANE]     = v.y;
        oc[2 * PLANE] = v.z;
        oc[3 * PLANE] = v.w;
    }
}

extern "C" void kernel_launch(void* const* d_in, const int* in_sizes, int n_in,
                              void* d_out, int out_size, void* d_ws, size_t ws_size,
                              hipStream_t stream) {
    const float* xyz  = (const float*)d_in[0];
    const float* feat = (const float*)d_in[1];
    float* out = (float*)d_out;

    char* ws = (char*)d_ws;
    float4* SP = (float4*)(ws);                // 16384*16 = 262144
    int*    CS = (int*)   (ws + 262144);       // 4*401*4 = 6416 (total ~263 KB)

    preprocess  <<<BB,          1024, 0, stream>>>(xyz, SP, CS);
    query_gather<<<BB * NN / 4, 256,  0, stream>>>(xyz, SP, CS, feat, out);
}

// Round 8
// 102.214 us; speedup vs baseline: 1.2253x; 1.0474x over previous
//
#include <hip/hip_runtime.h>

// AnnularDilatedKNN: B=4, N=4096, C=64, SAMPLE=16, DILATED_RATE=2, r^2=256.
// Round 11: K2 latency attack. Cross-round evidence: K2 ~44-50us across
// 8x candidate-count changes => latency-bound, not work-bound (r3 counters:
// VALUBusy 29%, occ 57%, 70% stall). Two deltas vs round-10 (PASSED 107us):
//  - __launch_bounds__(256,8): 8 blocks/CU, 32 waves/CU (was 4/16).
//  - Query: 6 segment bounds hoisted up-front into named scalar regs
//    (wave-uniform -> s_loads, independent), inner loop processes 2 chunks
//    per iteration (v, v+64; second guarded, NO speculative addresses --
//    round-0's harness-proven dual-chunk pattern) => 2x loads in flight.
//  K1 verbatim from round 10 (passed). Rank extraction + gather verbatim.
//  Hit test bit-identical: sq=(x*x+y*y)+z*z, dot=(xi*xj+yi*yj)+zi*zj,
//  d2=(sqi+sqj)-2*dot, contract off. Clamped dup rows harmless (mask OR
//  idempotent).

#define BB 4
#define NN 4096
#define KK 16
#define PLANE (NN * KK)   // 65536
#define NC 20
#define NCELL2 (NC * NC)  // 400

__device__ __forceinline__ int cell1d(float v)
{
    int c = (int)floorf((v + 160.0f) * 0.0625f);
    c = c < 0 ? 0 : c;
    return c > (NC - 1) ? (NC - 1) : c;
}

// ---------- K1: per-batch 2D histogram -> scan -> scatter (1 block/batch) ----------
// 1024 threads; thread t owns points 4t..4t+3 of its batch.
__global__ __launch_bounds__(1024)
void preprocess(const float* __restrict__ xyz, float4* __restrict__ SP,
                int* __restrict__ CS)
{
#pragma clang fp contract(off)
    __shared__ int hist[NCELL2];

    const int b = blockIdx.x;
    const int t = threadIdx.x;
    const float4* xb4 = (const float4*)(xyz + (size_t)b * NN * 3);

    if (t < NCELL2) hist[t] = 0;
    __syncthreads();

    // load 4 consecutive points (3 coalesced float4), keep in registers
    const float4 v0 = xb4[3 * t];
    const float4 v1 = xb4[3 * t + 1];
    const float4 v2 = xb4[3 * t + 2];
    const float px0 = v0.x, py0 = v0.y, pz0 = v0.z;
    const float px1 = v0.w, py1 = v1.x, pz1 = v1.y;
    const float px2 = v1.z, py2 = v1.w, pz2 = v2.x;
    const float px3 = v2.y, py3 = v2.z, pz3 = v2.w;
    const int c0 = cell1d(py0) * NC + cell1d(px0);
    const int c1 = cell1d(py1) * NC + cell1d(px1);
    const int c2 = cell1d(py2) * NC + cell1d(px2);
    const int c3 = cell1d(py3) * NC + cell1d(px3);
    atomicAdd(&hist[c0], 1);
    atomicAdd(&hist[c1], 1);
    atomicAdd(&hist[c2], 1);
    atomicAdd(&hist[c3], 1);
    __syncthreads();

    // wave 0 scans the 400 cells (7 cells per lane, statically indexed)
    if (t < 64) {
        const int base = t * 7;
        int loc0 = 0, loc1 = 0, loc2 = 0, loc3 = 0, loc4 = 0, loc5 = 0, loc6 = 0;
        if (base + 0 < NCELL2) loc0 = hist[base + 0];
        if (base + 1 < NCELL2) loc1 = hist[base + 1];
        if (base + 2 < NCELL2) loc2 = hist[base + 2];
        if (base + 3 < NCELL2) loc3 = hist[base + 3];
        if (base + 4 < NCELL2) loc4 = hist[base + 4];
        if (base + 5 < NCELL2) loc5 = hist[base + 5];
        if (base + 6 < NCELL2) loc6 = hist[base + 6];
        const int s = loc0 + loc1 + loc2 + loc3 + loc4 + loc5 + loc6;
        int x = s;
#pragma unroll
        for (int off = 1; off < 64; off <<= 1) {
            const int u = __shfl_up(x, off, 64);
            if (t >= off) x += u;
        }
        int acc = x - s;                       // exclusive prefix
        int* cs = CS + b * (NCELL2 + 1);
        if (base + 0 < NCELL2) { cs[base + 0] = acc; hist[base + 0] = acc; acc += loc0; }
        if (base + 1 < NCELL2) { cs[base + 1] = acc; hist[base + 1] = acc; acc += loc1; }
        if (base + 2 < NCELL2) { cs[base + 2] = acc; hist[base + 2] = acc; acc += loc2; }
        if (base + 3 < NCELL2) { cs[base + 3] = acc; hist[base + 3] = acc; acc += loc3; }
        if (base + 4 < NCELL2) { cs[base + 4] = acc; hist[base + 4] = acc; acc += loc4; }
        if (base + 5 < NCELL2) { cs[base + 5] = acc; hist[base + 5] = acc; acc += loc5; }
        if (base + 6 < NCELL2) { cs[base + 6] = acc; hist[base + 6] = acc; acc += loc6; }
        if (t == 0) cs[NCELL2] = NN;
    }
    __syncthreads();

    // scatter from registers; SP.w carries original index
    {
        int slot;
        slot = atomicAdd(&hist[c0], 1);
        SP[(b << 12) + slot] = make_float4(px0, py0, pz0, __int_as_float(4 * t + 0));
        slot = atomicAdd(&hist[c1], 1);
        SP[(b << 12) + slot] = make_float4(px1, py1, pz1, __int_as_float(4 * t + 1));
        slot = atomicAdd(&hist[c2], 1);
        SP[(b << 12) + slot] = make_float4(px2, py2, pz2, __int_as_float(4 * t + 2));
        slot = atomicAdd(&hist[c3], 1);
        SP[(b << 12) + slot] = make_float4(px3, py3, pz3, __int_as_float(4 * t + 3));
    }
}

// ---------- K2: fused grid ball query + gather ----------
// grid: 4096 blocks x 256 threads; block handles 4 consecutive points
// (ORIGINAL order), wave w queries point p0+w via 3 contiguous runs.
__global__ __launch_bounds__(256, 8)
void query_gather(const float* __restrict__ xyz, const float4* __restrict__ SP,
                  const int* __restrict__ CS, const float* __restrict__ feat,
                  float* __restrict__ out)
{
#pragma clang fp contract(off)
    __shared__ unsigned int mask[4][128];   // 4096-bit hit mask per point
    __shared__ int sids[4 * KK];

    const int beta = blockIdx.x;
    const int b    = beta >> 10;
    const int p0   = (beta & 1023) * 4;
    const int t    = threadIdx.x;
    const int lane = t & 63;
    const int wave = t >> 6;

    const float* xb   = xyz + (size_t)b * NN * 3;
    const float4* Sb  = SP + (b << 12);
    const int*    csb = CS + b * (NCELL2 + 1);

    // own point (original order): wave-uniform scalar loads, sq bit-identical
    const int   ip  = p0 + wave;
    const float pix = xb[3 * ip];
    const float piy = xb[3 * ip + 1];
    const float piz = xb[3 * ip + 2];
    const float sqi = (pix * pix + piy * piy) + piz * piz;

    // zero own mask (own-wave use only -> no barrier needed before query)
    unsigned int* m = mask[wave];
    m[2 * lane]     = 0u;
    m[2 * lane + 1] = 0u;

    // ---- query: 3 y-rows, bounds hoisted to named scalars, dual-chunk loop ----
    {
        const int cx = cell1d(pix), cy = cell1d(piy);
        const int xlo = cx > 0 ? cx - 1 : 0;
        const int xhi = cx < NC - 1 ? cx + 1 : NC - 1;
        const int yA = (cy - 1) < 0 ? 0 : cy - 1;            // dup rows harmless (OR)
        const int yC = (cy + 1) > NC - 1 ? NC - 1 : cy + 1;

        // all 6 bounds issued up-front, independent wave-uniform loads
        const int sA = csb[yA * NC + xlo], eA = csb[yA * NC + xhi + 1];
        const int sB = csb[cy * NC + xlo], eB = csb[cy * NC + xhi + 1];
        const int sC = csb[yC * NC + xlo], eC = csb[yC * NC + xhi + 1];

#pragma unroll
        for (int rr = 0; rr < 3; ++rr) {
            const int s = rr == 0 ? sA : (rr == 1 ? sB : sC);
            const int e = rr == 0 ? eA : (rr == 1 ? eB : eC);
            for (int v = s + lane; v < e; v += 128) {         // 2 chunks/iter
                const float4 a = Sb[v];
                const int v2   = v + 64;
                const bool h2  = v2 < e;
                float4 c2;
                if (h2) c2 = Sb[v2];                          // guarded, no spec
                const float sqa = (a.x * a.x + a.y * a.y) + a.z * a.z;
                const float da  = (pix * a.x + piy * a.y) + piz * a.z;
                const float d2a = (sqi + sqa) - 2.0f * da;
                if (d2a < 256.0f) {
                    const int j = __float_as_int(a.w);
                    atomicOr(&m[j >> 5], 1u << (j & 31));
                }
                if (h2) {
                    const float sqc = (c2.x * c2.x + c2.y * c2.y) + c2.z * c2.z;
                    const float dc  = (pix * c2.x + piy * c2.y) + piz * c2.z;
                    const float d2c = (sqi + sqc) - 2.0f * dc;
                    if (d2c < 256.0f) {
                        const int j = __float_as_int(c2.w);
                        atomicOr(&m[j >> 5], 1u << (j & 31));
                    }
                }
            }
        }
    }

    // ---- rank extraction: lane l owns indices [64l, 64l+64) (own mask) ----
    {
        const unsigned int lo  = m[2 * lane];
        const unsigned int hiw = m[2 * lane + 1];
        const unsigned long long w = ((unsigned long long)hiw << 32) | lo;
        const int c = __popcll(w);
        int x = c;                                  // inclusive scan of counts
#pragma unroll
        for (int off = 1; off < 64; off <<= 1) {
            const int u = __shfl_up(x, off, 64);
            if (lane >= off) x += u;
        }
        const int cnt  = __shfl(x, 63, 64);         // total hits
        const int base = x - c;                     // hits before this lane

        int fj = 0x7fffffff;                        // global first hit
        if (w) fj = (lane << 6) + __builtin_ctzll(w);
        for (int off = 32; off; off >>= 1) {
            const int o = __shfl_xor(fj, off, 64);
            fj = fj < o ? fj : o;
        }

        int* row = sids + wave * KK;
        if (w && base <= 30 && base + c > 16) {     // lane covers ranks 16..30?
            unsigned long long ww = w;
            int r = base;
            while (ww) {
                if (r > 30) break;
                if (r >= 16) row[r - 15] = (lane << 6) + __builtin_ctzll(ww);
                ww &= ww - 1;
                ++r;
            }
        }
        const int hi = (cnt < 31 ? cnt : 31) - 16;
        if (lane < KK && (lane == 0 || lane > hi)) row[lane] = fj;
    }
    __syncthreads();

    // ---- gather: thread t -> output row (t&63), channel quarter (t>>6) ----
    const int rowi = t & 63;
    const int part = t >> 6;
    const int id   = sids[rowi];
    const int ob   = (beta & 1023) * 64 + rowi;

    if (part == 0) {                                // dilated_xyz [B,3,N,K]
        float* o0 = out + (size_t)b * 3 * PLANE + ob;
        o0[0]         = xb[3 * id];
        o0[PLANE]     = xb[3 * id + 1];
        o0[2 * PLANE] = xb[3 * id + 2];
    }

    // dilated_feature [B,64,N,K], channels [16*part, 16*part+16)
    const float4* frow = reinterpret_cast<const float4*>(feat + ((size_t)(b << 12) + id) * 64) + part * 4;
    float* o1 = out + (size_t)BB * 3 * PLANE + (size_t)b * 64 * PLANE
                    + (size_t)(part * 16) * PLANE + ob;
#pragma unroll
    for (int q = 0; q < 4; ++q) {
        const float4 v = frow[q];
        float* oc = o1 + (size_t)(4 * q) * PLANE;
        oc[0]         = v.x;
        oc[PLANE]     = v.y;
        oc[2 * PLANE] = v.z;
        oc[3 * PLANE] = v.w;
    }
}

extern "C" void kernel_launch(void* const* d_in, const int* in_sizes, int n_in,
                              void* d_out, int out_size, void* d_ws, size_t ws_size,
                              hipStream_t stream) {
    const float* xyz  = (const float*)d_in[0];
    const float* feat = (const float*)d_in[1];
    float* out = (float*)d_out;

    char* ws = (char*)d_ws;
    float4* SP = (float4*)(ws);                // 16384*16 = 262144
    int*    CS = (int*)   (ws + 262144);       // 4*401*4 = 6416 (total ~263 KB)

    preprocess  <<<BB,          1024, 0, stream>>>(xyz, SP, CS);
    query_gather<<<BB * NN / 4, 256,  0, stream>>>(xyz, SP, CS, feat, out);
}